// Round 20
// baseline (446.495 us; speedup 1.0000x reference)
//
#include <hip/hip_runtime.h>
#include <hip/hip_bf16.h>

#define D128 128

typedef __attribute__((ext_vector_type(8))) short bf16x8;
typedef __attribute__((ext_vector_type(4))) float f32x4;
typedef __attribute__((ext_vector_type(2))) float f32x2;
typedef unsigned int uint;
typedef unsigned short ushort_t;

union U4 { uint4 u; bf16x8 h; };
__device__ __forceinline__ bf16x8 as_h(uint4 u) { U4 x; x.u = u; return x.h; }

__device__ __forceinline__ short f2bf(float f) {
  union { float f; unsigned u; } v; v.f = f;
  unsigned r = v.u + 0x7FFFu + ((v.u >> 16) & 1u);  // RNE
  return (short)(r >> 16);
}
__device__ __forceinline__ float bf_lo(uint v) {
  union { uint u; float f; } x; x.u = v << 16; return x.f;
}
__device__ __forceinline__ float bf_hi(uint v) {
  union { uint u; float f; } x; x.u = v & 0xFFFF0000u; return x.f;
}
__device__ __forceinline__ uint pack2(float a, float b) {
  return (uint)(unsigned short)f2bf(a) | ((uint)(unsigned short)f2bf(b) << 16);
}

// bf16 row write, 64B-contiguous per node per instruction (R16-proven)
__device__ __forceinline__ void store_pair_bf16(ushort_t* rowp, int r,
                                                int t0, int t1, float a, float b) {
  float sa = __shfl_xor(a, 1);
  float sb = __shfl_xor(b, 1);
  uint w; int colb;
  if ((r & 1) == 0) { w = pack2(a, sa); colb = t0 * 16 + r; }
  else             { w = pack2(sb, b); colb = t1 * 16 + (r - 1); }
  *(uint*)(rowp + colb) = w;
}

// ---- 4 weight tensors in one launch ----
__global__ __launch_bounds__(256)
void cvtW_k(const float* __restrict__ w0, const float* __restrict__ w1,
            const float* __restrict__ w2, const float* __restrict__ w3,
            ushort_t* __restrict__ o0, ushort_t* __restrict__ o1,
            ushort_t* __restrict__ o2, ushort_t* __restrict__ o3) {
  int y = blockIdx.y;
  const float* in = y == 0 ? w0 : y == 1 ? w1 : y == 2 ? w2 : w3;
  ushort_t* out = y == 0 ? o0 : y == 1 ? o1 : y == 2 ? o2 : o3;
  int i = blockIdx.x * 256 + threadIdx.x;
  if (i >= 16384) return;
  float4 v = ((const float4*)in)[i];
  ushort4 o;
  o.x = (unsigned short)f2bf(v.x); o.y = (unsigned short)f2bf(v.y);
  o.z = (unsigned short)f2bf(v.z); o.w = (unsigned short)f2bf(v.w);
  ((ushort4*)out)[i] = o;
}

// ---- fused preprocessing, interleaved cvt ∥ poscount (R11-proven) ----
__global__ __launch_bounds__(256)
void pre2_k(const float* __restrict__ ia, const float* __restrict__ im,
            const float* __restrict__ id, ushort_t* __restrict__ oa,
            ushort_t* __restrict__ om, ushort_t* __restrict__ od,
            int na4, int nm4, int nd4, int nbC,
            const int* __restrict__ d0, const int* __restrict__ d1,
            const int* __restrict__ d2, const int* __restrict__ d3,
            int* __restrict__ cnt, int* __restrict__ pos,
            int nE, int nbE4, int nbA,
            int b0, int b1, int b2, int b3) {
  int bx = blockIdx.x, tid = threadIdx.x;
  int total = nbC + nbA;
  long long s = ((long long)bx * nbA) / total;
  long long t = ((long long)(bx + 1) * nbA) / total;
  if (t > s) {
    int ab = (int)s;
    int y = ab / nbE4;
    int blk = ab - y * nbE4;
    const int* d = y == 0 ? d0 : y == 1 ? d1 : y == 2 ? d2 : d3;
    int base = y == 0 ? b0 : y == 1 ? b1 : y == 2 ? b2 : b3;
#pragma unroll
    for (int u = 0; u < 4; u++) {
      int i = blk * 1024 + u * 256 + tid;
      if (i < nE) {
        int p = atomicAdd(&cnt[base + d[i]], 1);
        pos[(size_t)y * nE + i] = p;
      }
    }
  } else {
    int i = (int)(bx - s) * 256 + tid;
    const float* in; ushort_t* out; int k;
    if (i < na4) { in = ia; out = oa; k = i; }
    else if (i < na4 + nm4) { in = im; out = om; k = i - na4; }
    else if (i < na4 + nm4 + nd4) { in = id; out = od; k = i - na4 - nm4; }
    else return;
    float4 v = ((const float4*)in)[k];
    ushort4 o;
    o.x = (unsigned short)f2bf(v.x); o.y = (unsigned short)f2bf(v.y);
    o.z = (unsigned short)f2bf(v.z); o.w = (unsigned short)f2bf(v.w);
    ((ushort4*)out)[k] = o;
  }
}

// ---- scan stage 1 ----
__device__ __forceinline__ int wave_incl_scan(int v, int lane) {
#pragma unroll
  for (int off = 1; off < 64; off <<= 1) {
    int y = __shfl_up(v, off);
    if (lane >= off) v += y;
  }
  return v;
}

__global__ __launch_bounds__(256) void scan1_k(const int* __restrict__ cnt,
                                               int* __restrict__ bsum, int n) {
  int b = blockIdx.x, tid = threadIdx.x;
  int i = b * 256 + tid;
  int v = (i < n) ? cnt[i] : 0;
  int lane = tid & 63, wid = tid >> 6;
  __shared__ int ws[4];
  int s = wave_incl_scan(v, lane);
  if (lane == 63) ws[wid] = s;
  __syncthreads();
  if (tid == 0) bsum[b] = ws[0] + ws[1] + ws[2] + ws[3];
}

// ---- scan stage 2 (+ inv fold) ----
__global__ __launch_bounds__(256) void scan2_k(const int* __restrict__ cnt,
                                               const int* __restrict__ bsum,
                                               int* __restrict__ ofs,
                                               float* __restrict__ inv, int n) {
  int b = blockIdx.x, tid = threadIdx.x;
  int lane = tid & 63, wid = tid >> 6;
  __shared__ int wsA[4], wsB[4];
  int p = 0;
  for (int j = tid; j < b; j += 256) p += bsum[j];
#pragma unroll
  for (int off = 32; off; off >>= 1) p += __shfl_xor(p, off);
  if (lane == 0) wsA[wid] = p;
  __syncthreads();
  int base = wsA[0] + wsA[1] + wsA[2] + wsA[3];
  int i = b * 256 + tid;
  int v = (i < n) ? cnt[i] : 0;
  int s = wave_incl_scan(v, lane);
  if (lane == 63) wsB[wid] = s;
  __syncthreads();
  int woff = 0;
  for (int w = 0; w < wid; w++) woff += wsB[w];
  int excl = base + woff + s - v;
  if (i < n) {
    ofs[i] = excl;
    inv[i] = 1.0f / (float)(v > 1 ? v : 1);
  }
}

// ---- reorder: bucket fill with NO atomics, 2 edges/thread ----
__global__ __launch_bounds__(256)
void reorder4_k(const int* __restrict__ e0, const int* __restrict__ e1,
                const int* __restrict__ e2, const int* __restrict__ e3,
                const int* __restrict__ ofs, const int* __restrict__ pos,
                int* __restrict__ bucket,
                int nE, int b0, int b1, int b2, int b3) {
  int y = blockIdx.y;
  const int* e = y == 0 ? e0 : y == 1 ? e1 : y == 2 ? e2 : e3;
  int base = y == 0 ? b0 : y == 1 ? b1 : y == 2 ? b2 : b3;
#pragma unroll
  for (int u = 0; u < 2; u++) {
    int i = blockIdx.x * 512 + u * 256 + threadIdx.x;
    if (i < nE) {
      int s = e[i];
      int d = e[nE + i];
      int p = pos[(size_t)y * nE + i];
      bucket[ofs[base + d] + p] = s;
    }
  }
}

// ---- accumulate one loaded row (4x uint4) into f32 partials ----
__device__ __forceinline__ void acc_row(f32x2 a[4][4], uint4 v0, uint4 v1,
                                        uint4 v2, uint4 v3) {
  a[0][0] += (f32x2){bf_lo(v0.x), bf_hi(v0.x)};
  a[0][1] += (f32x2){bf_lo(v0.y), bf_hi(v0.y)};
  a[0][2] += (f32x2){bf_lo(v0.z), bf_hi(v0.z)};
  a[0][3] += (f32x2){bf_lo(v0.w), bf_hi(v0.w)};
  a[1][0] += (f32x2){bf_lo(v1.x), bf_hi(v1.x)};
  a[1][1] += (f32x2){bf_lo(v1.y), bf_hi(v1.y)};
  a[1][2] += (f32x2){bf_lo(v1.z), bf_hi(v1.z)};
  a[1][3] += (f32x2){bf_lo(v1.w), bf_hi(v1.w)};
  a[2][0] += (f32x2){bf_lo(v2.x), bf_hi(v2.x)};
  a[2][1] += (f32x2){bf_lo(v2.y), bf_hi(v2.y)};
  a[2][2] += (f32x2){bf_lo(v2.z), bf_hi(v2.z)};
  a[2][3] += (f32x2){bf_lo(v2.w), bf_hi(v2.w)};
  a[3][0] += (f32x2){bf_lo(v3.x), bf_hi(v3.x)};
  a[3][1] += (f32x2){bf_lo(v3.y), bf_hi(v3.y)};
  a[3][2] += (f32x2){bf_lo(v3.z), bf_hi(v3.z)};
  a[3][3] += (f32x2){bf_lo(v3.w), bf_hi(v3.w)};
}

__device__ __forceinline__ void pack_frags(f32x2 ac[4][4], float iv, uint4 out[4]) {
#pragma unroll
  for (int kk = 0; kk < 4; kk++) {
    uint4 o;
    o.x = pack2(ac[kk][0][0] * iv, ac[kk][0][1] * iv);
    o.y = pack2(ac[kk][1][0] * iv, ac[kk][1][1] * iv);
    o.z = pack2(ac[kk][2][0] * iv, ac[kk][2][1] * iv);
    o.w = pack2(ac[kk][3][0] * iv, ac[kk][3][1] * iv);
    out[kk] = o;
  }
}

// ---- single-chain gather (R18-proven explicit two-row unroll-2) ----
__device__ __forceinline__ void gather_frags(const ushort_t* __restrict__ xsrc,
                                             const int* __restrict__ bucket,
                                             int beg, int c, float iv, int kh,
                                             uint4 out[4]) {
  f32x2 ac[4][4];
#pragma unroll
  for (int kk = 0; kk < 4; kk++)
#pragma unroll
    for (int p = 0; p < 4; p++) ac[kk][p] = (f32x2){0.f, 0.f};

  const ushort_t* base = xsrc + kh * 8;
  int j = 0;
  for (; j + 2 <= c; j += 2) {
    const ushort_t* r0 = base + (size_t)bucket[beg + j] * D128;
    const ushort_t* r1 = base + (size_t)bucket[beg + j + 1] * D128;
    uint4 v00 = *(const uint4*)(r0);
    uint4 v01 = *(const uint4*)(r0 + 32);
    uint4 v02 = *(const uint4*)(r0 + 64);
    uint4 v03 = *(const uint4*)(r0 + 96);
    uint4 v10 = *(const uint4*)(r1);
    uint4 v11 = *(const uint4*)(r1 + 32);
    uint4 v12 = *(const uint4*)(r1 + 64);
    uint4 v13 = *(const uint4*)(r1 + 96);
    acc_row(ac, v00, v01, v02, v03);
    acc_row(ac, v10, v11, v12, v13);
  }
  if (j < c) {
    const ushort_t* r0 = base + (size_t)bucket[beg + j] * D128;
    acc_row(ac, *(const uint4*)(r0), *(const uint4*)(r0 + 32),
            *(const uint4*)(r0 + 64), *(const uint4*)(r0 + 96));
  }
  pack_frags(ac, iv, out);
}

// ---- dual-chain gather: A and B chains interleaved, branch-free addresses
//  (absent rows read row 0 -- L1-cached -- and skip only the accumulate;
//   per-chain accumulation order unchanged -> bit-identical numerics). ----
__device__ __forceinline__ void gather_frags2(
    const ushort_t* __restrict__ xsA, int begA, int cA, float ivA,
    const ushort_t* __restrict__ xsB, int begB, int cB, float ivB,
    const int* __restrict__ bucket, int kh, uint4 outA[4], uint4 outB[4]) {
  f32x2 acA[4][4], acB[4][4];
#pragma unroll
  for (int kk = 0; kk < 4; kk++)
#pragma unroll
    for (int p = 0; p < 4; p++) {
      acA[kk][p] = (f32x2){0.f, 0.f};
      acB[kk][p] = (f32x2){0.f, 0.f};
    }

  const ushort_t* baseA = xsA + kh * 8;
  const ushort_t* baseB = xsB + kh * 8;
  int cm = cA > cB ? cA : cB;
  for (int j = 0; j < cm; j++) {
    bool a = j < cA, b = j < cB;
    int iA = a ? bucket[begA + j] : 0;
    int iB = b ? bucket[begB + j] : 0;
    const ushort_t* rA = baseA + (size_t)iA * D128;
    const ushort_t* rB = baseB + (size_t)iB * D128;
    uint4 a0 = *(const uint4*)(rA);
    uint4 a1 = *(const uint4*)(rA + 32);
    uint4 a2 = *(const uint4*)(rA + 64);
    uint4 a3 = *(const uint4*)(rA + 96);
    uint4 b0 = *(const uint4*)(rB);
    uint4 b1 = *(const uint4*)(rB + 32);
    uint4 b2 = *(const uint4*)(rB + 64);
    uint4 b3 = *(const uint4*)(rB + 96);
    if (a) acc_row(acA, a0, a1, a2, a3);
    if (b) acc_row(acB, b0, b1, b2, b3);
  }
  pack_frags(acA, ivA, outA);
  pack_frags(acB, ivB, outB);
}

// ---- fused gather+SAGE, single edge type ----
struct SJob {
  const ushort_t* xs;   // gather source rows
  const int* ofs;
  const int* cnt;
  const float* inv;
  const ushort_t* xd;   // dense lin_r input
  const ushort_t* wl;
  const ushort_t* wr;
  const float* bias;
  ushort_t* out;
  int ntiles;
};

__device__ __forceinline__ void sage_single_fused(const SJob& J, char* smem,
                                                  const int* __restrict__ bucket) {
  const int tid = threadIdx.x;
  for (int c = tid; c < 4096; c += 1024) {
    int m = c >> 11, cc = c & 2047;
    int row = cc >> 4, slot = cc & 15;
    const ushort_t* W = m ? J.wr : J.wl;
    uint4 v = *((const uint4*)W + cc);
    *(uint4*)(smem + m * 32768 + row * 256 + ((slot ^ (row & 15)) << 4)) = v;
  }
  __syncthreads();

  int wid = tid >> 6, lane = tid & 63;
  int r = lane & 15, kh = lane >> 4;
  int tile = blockIdx.x * 16 + wid;
  if (tile >= J.ntiles) return;
  size_t n0 = (size_t)tile * 16;
  int node = (int)n0 + r;

  uint4 A4[4];
  gather_frags(J.xs, bucket, J.ofs[node], J.cnt[node], J.inv[node], kh, A4);

  const ushort_t* xp = J.xd + (n0 + r) * D128 + kh * 8;
  uint4 X4[4];
#pragma unroll
  for (int kk = 0; kk < 4; kk++) X4[kk] = *(const uint4*)(xp + kk * 32);

  f32x4 acc[8];
#pragma unroll
  for (int t = 0; t < 8; t++) acc[t] = (f32x4){0.f, 0.f, 0.f, 0.f};

#pragma unroll
  for (int kk = 0; kk < 4; kk++) {
    int so = (((kk << 2) + kh) ^ r) << 4;
    bf16x8 af = as_h(A4[kk]);
    bf16x8 xf = as_h(X4[kk]);
#pragma unroll
    for (int t = 0; t < 8; t++) {
      const char* p = smem + t * 4096 + r * 256 + so;
      bf16x8 bwl = *(const bf16x8*)(p);
      bf16x8 bwr = *(const bf16x8*)(p + 32768);
      acc[t] = __builtin_amdgcn_mfma_f32_16x16x32_bf16(af, bwl, acc[t], 0, 0, 0);
      acc[t] = __builtin_amdgcn_mfma_f32_16x16x32_bf16(xf, bwr, acc[t], 0, 0, 0);
    }
  }

  float s[4] = {0.f, 0.f, 0.f, 0.f};
#pragma unroll
  for (int t = 0; t < 8; t++) {
    float bv = J.bias[t * 16 + r];
#pragma unroll
    for (int q = 0; q < 4; q++) {
      float c = acc[t][q] + bv;
      acc[t][q] = c;
      s[q] += c * c;
    }
  }
#pragma unroll
  for (int off = 1; off < 16; off <<= 1) {
#pragma unroll
    for (int q = 0; q < 4; q++) s[q] += __shfl_xor(s[q], off);
  }
  float rn[4];
#pragma unroll
  for (int q = 0; q < 4; q++) rn[q] = 1.0f / fmaxf(sqrtf(s[q]), 1e-12f);

#pragma unroll
  for (int tp = 0; tp < 4; tp++) {
    int t0 = 2 * tp, t1 = 2 * tp + 1;
#pragma unroll
    for (int q = 0; q < 4; q++) {
      float a = fmaxf(acc[t0][q] * rn[q], 0.f);
      float b = fmaxf(acc[t1][q] * rn[q], 0.f);
      size_t nd = n0 + kh * 4 + q;
      store_pair_bf16(J.out + nd * D128, r, t0, t1, a, b);
    }
  }
}

// ---- fused gather+SAGE, dual edge type (app dst) ----
struct DJob {
  const ushort_t* xsA;
  const int* ofsA;
  const int* cntA;
  const float* invA;
  const ushort_t* xsB;
  const int* ofsB;
  const int* cntB;
  const float* invB;
  const ushort_t* xd;
  const ushort_t* wlA;
  const ushort_t* wrA;
  const ushort_t* wlB;
  const ushort_t* wrB;
  const float* biasA;
  const float* biasB;
  void* out;
  int ntiles;
};

template <int CLF>
__device__ __forceinline__ void sage_dual_fused(const DJob& J, char* smem,
                                                const int* __restrict__ bucket,
                                                const float* clfW, const float* clfb) {
  const int tid = threadIdx.x;
  for (int c = tid; c < 8192; c += 1024) {
    int m = c >> 11, cc = c & 2047;
    int row = cc >> 4, slot = cc & 15;
    const ushort_t* W = m == 0 ? J.wlA : m == 1 ? J.wrA : m == 2 ? J.wlB : J.wrB;
    uint4 v = *((const uint4*)W + cc);
    *(uint4*)(smem + m * 32768 + row * 256 + ((slot ^ (row & 15)) << 4)) = v;
  }
  __syncthreads();

  int wid = tid >> 6, lane = tid & 63;
  int r = lane & 15, kh = lane >> 4;
  int tile = blockIdx.x * 16 + wid;
  if (tile >= J.ntiles) return;
  size_t n0 = (size_t)tile * 16;
  int node = (int)n0 + r;

  uint4 A1[4], A3[4];
  gather_frags2(J.xsA, J.ofsA[node], J.cntA[node], J.invA[node],
                J.xsB, J.ofsB[node], J.cntB[node], J.invB[node],
                bucket, kh, A1, A3);

  const ushort_t* xp = J.xd + (n0 + r) * D128 + kh * 8;
  uint4 X4[4];
#pragma unroll
  for (int kk = 0; kk < 4; kk++) X4[kk] = *(const uint4*)(xp + kk * 32);

  f32x4 acc1[8], acc3[8];
#pragma unroll
  for (int t = 0; t < 8; t++) {
    acc1[t] = (f32x4){0.f, 0.f, 0.f, 0.f};
    acc3[t] = (f32x4){0.f, 0.f, 0.f, 0.f};
  }

#pragma unroll
  for (int kk = 0; kk < 4; kk++) {
    int so = (((kk << 2) + kh) ^ r) << 4;
    bf16x8 af1 = as_h(A1[kk]);
    bf16x8 af3 = as_h(A3[kk]);
    bf16x8 xf = as_h(X4[kk]);
#pragma unroll
    for (int t = 0; t < 8; t++) {
      const char* p = smem + t * 4096 + r * 256 + so;
      bf16x8 wla = *(const bf16x8*)(p);
      bf16x8 wra = *(const bf16x8*)(p + 32768);
      bf16x8 wlb = *(const bf16x8*)(p + 65536);
      bf16x8 wrb = *(const bf16x8*)(p + 98304);
      acc1[t] = __builtin_amdgcn_mfma_f32_16x16x32_bf16(af1, wla, acc1[t], 0, 0, 0);
      acc1[t] = __builtin_amdgcn_mfma_f32_16x16x32_bf16(xf, wra, acc1[t], 0, 0, 0);
      acc3[t] = __builtin_amdgcn_mfma_f32_16x16x32_bf16(af3, wlb, acc3[t], 0, 0, 0);
      acc3[t] = __builtin_amdgcn_mfma_f32_16x16x32_bf16(xf, wrb, acc3[t], 0, 0, 0);
    }
  }

  float s1[4] = {0.f, 0.f, 0.f, 0.f}, s3[4] = {0.f, 0.f, 0.f, 0.f};
#pragma unroll
  for (int t = 0; t < 8; t++) {
    float bvA = J.biasA[t * 16 + r];
    float bvB = J.biasB[t * 16 + r];
#pragma unroll
    for (int q = 0; q < 4; q++) {
      float c1 = acc1[t][q] + bvA;
      acc1[t][q] = c1; s1[q] += c1 * c1;
      float c3 = acc3[t][q] + bvB;
      acc3[t][q] = c3; s3[q] += c3 * c3;
    }
  }
#pragma unroll
  for (int off = 1; off < 16; off <<= 1) {
#pragma unroll
    for (int q = 0; q < 4; q++) {
      s1[q] += __shfl_xor(s1[q], off);
      s3[q] += __shfl_xor(s3[q], off);
    }
  }
  float rn1[4], rn3[4];
#pragma unroll
  for (int q = 0; q < 4; q++) {
    rn1[q] = 1.0f / fmaxf(sqrtf(s1[q]), 1e-12f);
    rn3[q] = 1.0f / fmaxf(sqrtf(s3[q]), 1e-12f);
  }

  if (CLF) {
    float w0[8], w1[8];
#pragma unroll
    for (int t = 0; t < 8; t++) {
      w0[t] = clfW[t * 16 + r];
      w1[t] = clfW[D128 + t * 16 + r];
    }
    float p0[4] = {0.f, 0.f, 0.f, 0.f}, p1[4] = {0.f, 0.f, 0.f, 0.f};
#pragma unroll
    for (int t = 0; t < 8; t++) {
#pragma unroll
      for (int q = 0; q < 4; q++) {
        float val = acc1[t][q] * rn1[q] + acc3[t][q] * rn3[q];
        p0[q] += val * w0[t];
        p1[q] += val * w1[t];
      }
    }
#pragma unroll
    for (int off = 1; off < 16; off <<= 1) {
#pragma unroll
      for (int q = 0; q < 4; q++) {
        p0[q] += __shfl_xor(p0[q], off);
        p1[q] += __shfl_xor(p1[q], off);
      }
    }
    if (r == 0) {
      float cb0 = clfb[0], cb1 = clfb[1];
#pragma unroll
      for (int q = 0; q < 4; q++) {
        size_t nd = n0 + kh * 4 + q;
        float2 o; o.x = p0[q] + cb0; o.y = p1[q] + cb1;
        *(float2*)((float*)J.out + nd * 2) = o;
      }
    }
  } else {
#pragma unroll
    for (int tp = 0; tp < 4; tp++) {
      int t0 = 2 * tp, t1 = 2 * tp + 1;
#pragma unroll
      for (int q = 0; q < 4; q++) {
        float a = fmaxf(acc1[t0][q] * rn1[q] + acc3[t0][q] * rn3[q], 0.f);
        float b = fmaxf(acc1[t1][q] * rn1[q] + acc3[t1][q] * rn3[q], 0.f);
        size_t nd = n0 + kh * 4 + q;
        store_pair_bf16((ushort_t*)J.out + nd * D128, r, t0, t1, a, b);
      }
    }
  }
}

// ---- L1: y=0 dual app (h1a), y=1 mer single, y=2 dev single ----
__global__ __launch_bounds__(1024)
void sageL1_k(DJob DJ, SJob S1, SJob S2, const int* __restrict__ bucket) {
  extern __shared__ char smem[];
  int y = blockIdx.y;
  if (y == 0) {
    sage_dual_fused<0>(DJ, smem, bucket, nullptr, nullptr);
  } else {
    const SJob& J = (y == 1) ? S1 : S2;
    if (blockIdx.x * 16 >= J.ntiles) return;
    sage_single_fused(J, smem, bucket);
  }
}

// ---- L2: dual + classifier ----
__global__ __launch_bounds__(1024)
void sageL2_k(DJob DJ, const int* __restrict__ bucket,
              const float* __restrict__ clfW, const float* __restrict__ clfb) {
  extern __shared__ char smem[];
  sage_dual_fused<1>(DJ, smem, bucket, clfW, clfb);
}

extern "C" void kernel_launch(void* const* d_in, const int* in_sizes, int n_in,
                              void* d_out, int out_size, void* d_ws, size_t ws_size,
                              hipStream_t stream) {
  const float* emb_app = (const float*)d_in[0];
  const float* emb_mer = (const float*)d_in[1];
  const float* emb_dev = (const float*)d_in[2];
  const float* c1Wl = (const float*)d_in[3];
  const float* c1bl = (const float*)d_in[4];
  const float* c1Wr = (const float*)d_in[5];
  const float* c2Wl = (const float*)d_in[6];
  const float* c2bl = (const float*)d_in[7];
  const float* c2Wr = (const float*)d_in[8];
  const float* clfW = (const float*)d_in[9];
  const float* clfb = (const float*)d_in[10];
  const int* e0 = (const int*)d_in[11];
  const int* e1 = (const int*)d_in[12];
  const int* e2 = (const int*)d_in[13];
  const int* e3 = (const int*)d_in[14];

  const int NA = in_sizes[0] / D128;
  const int NM = in_sizes[1] / D128;
  const int ND = in_sizes[2] / D128;
  const int E = in_sizes[11] / 2;
  float* out = (float*)d_out;

  char* wsb = (char*)d_ws;
  size_t off = 0;
  auto alloc = [&](size_t bytes) -> char* {
    char* p = wsb + off;
    off += (bytes + 511) & ~(size_t)511;
    return p;
  };
  ushort_t* wl1 = (ushort_t*)alloc((size_t)4 * 16384 * 2);
  ushort_t* wr1 = (ushort_t*)alloc((size_t)4 * 16384 * 2);
  ushort_t* wl2 = (ushort_t*)alloc((size_t)4 * 16384 * 2);
  ushort_t* wr2 = (ushort_t*)alloc((size_t)4 * 16384 * 2);

  // embeddings bf16 (live through layer 1)
  size_t embBytes = ((size_t)NM + ND + NA) * D128 * 2;
  char* big = alloc(embBytes);
  ushort_t* emer = (ushort_t*)big;
  ushort_t* edev = emer + (size_t)NM * D128;
  ushort_t* eapp = edev + (size_t)ND * D128;

  ushort_t* h1m = (ushort_t*)alloc((size_t)NM * D128 * 2);
  ushort_t* h1d = (ushort_t*)alloc((size_t)ND * D128 * 2);
  ushort_t* h1a = (ushort_t*)alloc((size_t)NA * D128 * 2);
  int ncnt = NM + NA + ND + NA;
  int nb = (ncnt + 255) / 256;
  int* cnt = (int*)alloc((size_t)ncnt * 4);
  float* inv = (float*)alloc((size_t)ncnt * 4);
  int* ofs = (int*)alloc((size_t)ncnt * 4);
  int* bsum = (int*)alloc((size_t)nb * 4);
  int* pos = (int*)alloc((size_t)4 * E * 4);
  int* bucket = (int*)alloc((size_t)4 * E * 4);
  (void)ws_size;  // ~205 MB

  int b0 = 0, b1 = NM, b2 = NM + NA, b3 = NM + NA + ND;

  const int SMEM2 = 131072;
  hipFuncSetAttribute((const void*)sageL1_k,
                      hipFuncAttributeMaxDynamicSharedMemorySize, SMEM2);
  hipFuncSetAttribute((const void*)sageL2_k,
                      hipFuncAttributeMaxDynamicSharedMemorySize, SMEM2);

  // ---- weights cvt + interleaved {embedding cvt ∥ poscount} ----
  dim3 wg(64, 4);
  cvtW_k<<<wg, 256, 0, stream>>>(c1Wl, c1Wr, c2Wl, c2Wr, wl1, wr1, wl2, wr2);
  hipMemsetAsync(cnt, 0, (size_t)ncnt * 4, stream);
  int na4 = NA * 32, nm4 = NM * 32, nd4 = ND * 32;
  int nbC = (na4 + nm4 + nd4 + 255) / 256;
  int nbE4 = (E + 1023) / 1024;
  int nbA = 4 * nbE4;
  pre2_k<<<nbC + nbA, 256, 0, stream>>>(
      emb_app, emb_mer, emb_dev, eapp, emer, edev, na4, nm4, nd4, nbC,
      e0 + E, e1 + E, e2 + E, e3 + E, cnt, pos, E, nbE4, nbA, b0, b1, b2, b3);
  scan1_k<<<nb, 256, 0, stream>>>(cnt, bsum, ncnt);
  scan2_k<<<nb, 256, 0, stream>>>(cnt, bsum, ofs, inv, ncnt);
  dim3 eg((E + 511) / 512, 4);
  reorder4_k<<<eg, 256, 0, stream>>>(e0, e1, e2, e3, ofs, pos, bucket,
                                     E, b0, b1, b2, b3);

  auto g16 = [](int nt) { return (nt + 15) / 16; };
  int tA = NA / 16, tM = NM / 16, tD = ND / 16;

  // ---- layer 1: all 4 gathers fused into the 3 sage jobs, one launch ----
  {
    DJob DJ;
    DJ.xsA = emer; DJ.ofsA = ofs + b1; DJ.cntA = cnt + b1; DJ.invA = inv + b1;
    DJ.xsB = edev; DJ.ofsB = ofs + b3; DJ.cntB = cnt + b3; DJ.invB = inv + b3;
    DJ.xd = eapp;
    DJ.wlA = wl1 + 1 * 16384; DJ.wrA = wr1 + 1 * 16384;
    DJ.wlB = wl1 + 3 * 16384; DJ.wrB = wr1 + 3 * 16384;
    DJ.biasA = c1bl + 1 * D128; DJ.biasB = c1bl + 3 * D128;
    DJ.out = h1a; DJ.ntiles = tA;
    SJob S1;
    S1.xs = eapp; S1.ofs = ofs + b0; S1.cnt = cnt + b0; S1.inv = inv + b0;
    S1.xd = emer; S1.wl = wl1 + 0 * 16384; S1.wr = wr1 + 0 * 16384;
    S1.bias = c1bl + 0 * D128; S1.out = h1m; S1.ntiles = tM;
    SJob S2;
    S2.xs = eapp; S2.ofs = ofs + b2; S2.cnt = cnt + b2; S2.inv = inv + b2;
    S2.xd = edev; S2.wl = wl1 + 2 * 16384; S2.wr = wr1 + 2 * 16384;
    S2.bias = c1bl + 2 * D128; S2.out = h1d; S2.ntiles = tD;
    dim3 sg(g16(tA), 3);
    sageL1_k<<<sg, 1024, SMEM2, stream>>>(DJ, S1, S2, bucket);
  }

  // ---- layer 2: fused gathers (h1m/h1d post-relu) + dual + classifier ----
  {
    DJob DJ;
    DJ.xsA = h1m; DJ.ofsA = ofs + b1; DJ.cntA = cnt + b1; DJ.invA = inv + b1;
    DJ.xsB = h1d; DJ.ofsB = ofs + b3; DJ.cntB = cnt + b3; DJ.invB = inv + b3;
    DJ.xd = h1a;
    DJ.wlA = wl2 + 1 * 16384; DJ.wrA = wr2 + 1 * 16384;
    DJ.wlB = wl2 + 3 * 16384; DJ.wrB = wr2 + 3 * 16384;
    DJ.biasA = c2bl + 1 * D128; DJ.biasB = c2bl + 3 * D128;
    DJ.out = out; DJ.ntiles = tA;
    sageL2_k<<<g16(tA), 1024, SMEM2, stream>>>(DJ, bucket, clfW, clfb);
  }
}

// Round 21
// 438.843 us; speedup vs baseline: 1.0174x; 1.0174x over previous
//
#include <hip/hip_runtime.h>
#include <hip/hip_bf16.h>

#define D128 128

typedef __attribute__((ext_vector_type(8))) short bf16x8;
typedef __attribute__((ext_vector_type(4))) float f32x4;
typedef __attribute__((ext_vector_type(2))) float f32x2;
typedef unsigned int uint;
typedef unsigned short ushort_t;

union U4 { uint4 u; bf16x8 h; };
__device__ __forceinline__ bf16x8 as_h(uint4 u) { U4 x; x.u = u; return x.h; }

__device__ __forceinline__ short f2bf(float f) {
  union { float f; unsigned u; } v; v.f = f;
  unsigned r = v.u + 0x7FFFu + ((v.u >> 16) & 1u);  // RNE
  return (short)(r >> 16);
}
__device__ __forceinline__ float bf_lo(uint v) {
  union { uint u; float f; } x; x.u = v << 16; return x.f;
}
__device__ __forceinline__ float bf_hi(uint v) {
  union { uint u; float f; } x; x.u = v & 0xFFFF0000u; return x.f;
}
__device__ __forceinline__ uint pack2(float a, float b) {
  return (uint)(unsigned short)f2bf(a) | ((uint)(unsigned short)f2bf(b) << 16);
}

// bf16 row write, 64B-contiguous per node per instruction (R16-proven)
__device__ __forceinline__ void store_pair_bf16(ushort_t* rowp, int r,
                                                int t0, int t1, float a, float b) {
  float sa = __shfl_xor(a, 1);
  float sb = __shfl_xor(b, 1);
  uint w; int colb;
  if ((r & 1) == 0) { w = pack2(a, sa); colb = t0 * 16 + r; }
  else             { w = pack2(sb, b); colb = t1 * 16 + (r - 1); }
  *(uint*)(rowp + colb) = w;
}

// ---- 4 weight tensors in one launch ----
__global__ __launch_bounds__(256)
void cvtW_k(const float* __restrict__ w0, const float* __restrict__ w1,
            const float* __restrict__ w2, const float* __restrict__ w3,
            ushort_t* __restrict__ o0, ushort_t* __restrict__ o1,
            ushort_t* __restrict__ o2, ushort_t* __restrict__ o3) {
  int y = blockIdx.y;
  const float* in = y == 0 ? w0 : y == 1 ? w1 : y == 2 ? w2 : w3;
  ushort_t* out = y == 0 ? o0 : y == 1 ? o1 : y == 2 ? o2 : o3;
  int i = blockIdx.x * 256 + threadIdx.x;
  if (i >= 16384) return;
  float4 v = ((const float4*)in)[i];
  ushort4 o;
  o.x = (unsigned short)f2bf(v.x); o.y = (unsigned short)f2bf(v.y);
  o.z = (unsigned short)f2bf(v.z); o.w = (unsigned short)f2bf(v.w);
  ((ushort4*)out)[i] = o;
}

// ---- fused preprocessing, interleaved cvt ∥ poscount (R11-proven) ----
__global__ __launch_bounds__(256)
void pre2_k(const float* __restrict__ ia, const float* __restrict__ im,
            const float* __restrict__ id, ushort_t* __restrict__ oa,
            ushort_t* __restrict__ om, ushort_t* __restrict__ od,
            int na4, int nm4, int nd4, int nbC,
            const int* __restrict__ d0, const int* __restrict__ d1,
            const int* __restrict__ d2, const int* __restrict__ d3,
            int* __restrict__ cnt, int* __restrict__ pos,
            int nE, int nbE4, int nbA,
            int b0, int b1, int b2, int b3) {
  int bx = blockIdx.x, tid = threadIdx.x;
  int total = nbC + nbA;
  long long s = ((long long)bx * nbA) / total;
  long long t = ((long long)(bx + 1) * nbA) / total;
  if (t > s) {
    int ab = (int)s;
    int y = ab / nbE4;
    int blk = ab - y * nbE4;
    const int* d = y == 0 ? d0 : y == 1 ? d1 : y == 2 ? d2 : d3;
    int base = y == 0 ? b0 : y == 1 ? b1 : y == 2 ? b2 : b3;
#pragma unroll
    for (int u = 0; u < 4; u++) {
      int i = blk * 1024 + u * 256 + tid;
      if (i < nE) {
        int p = atomicAdd(&cnt[base + d[i]], 1);
        pos[(size_t)y * nE + i] = p;
      }
    }
  } else {
    int i = (int)(bx - s) * 256 + tid;
    const float* in; ushort_t* out; int k;
    if (i < na4) { in = ia; out = oa; k = i; }
    else if (i < na4 + nm4) { in = im; out = om; k = i - na4; }
    else if (i < na4 + nm4 + nd4) { in = id; out = od; k = i - na4 - nm4; }
    else return;
    float4 v = ((const float4*)in)[k];
    ushort4 o;
    o.x = (unsigned short)f2bf(v.x); o.y = (unsigned short)f2bf(v.y);
    o.z = (unsigned short)f2bf(v.z); o.w = (unsigned short)f2bf(v.w);
    ((ushort4*)out)[k] = o;
  }
}

// ---- scan stage 1 ----
__device__ __forceinline__ int wave_incl_scan(int v, int lane) {
#pragma unroll
  for (int off = 1; off < 64; off <<= 1) {
    int y = __shfl_up(v, off);
    if (lane >= off) v += y;
  }
  return v;
}

__global__ __launch_bounds__(256) void scan1_k(const int* __restrict__ cnt,
                                               int* __restrict__ bsum, int n) {
  int b = blockIdx.x, tid = threadIdx.x;
  int i = b * 256 + tid;
  int v = (i < n) ? cnt[i] : 0;
  int lane = tid & 63, wid = tid >> 6;
  __shared__ int ws[4];
  int s = wave_incl_scan(v, lane);
  if (lane == 63) ws[wid] = s;
  __syncthreads();
  if (tid == 0) bsum[b] = ws[0] + ws[1] + ws[2] + ws[3];
}

// ---- scan stage 2 (+ inv fold) ----
__global__ __launch_bounds__(256) void scan2_k(const int* __restrict__ cnt,
                                               const int* __restrict__ bsum,
                                               int* __restrict__ ofs,
                                               float* __restrict__ inv, int n) {
  int b = blockIdx.x, tid = threadIdx.x;
  int lane = tid & 63, wid = tid >> 6;
  __shared__ int wsA[4], wsB[4];
  int p = 0;
  for (int j = tid; j < b; j += 256) p += bsum[j];
#pragma unroll
  for (int off = 32; off; off >>= 1) p += __shfl_xor(p, off);
  if (lane == 0) wsA[wid] = p;
  __syncthreads();
  int base = wsA[0] + wsA[1] + wsA[2] + wsA[3];
  int i = b * 256 + tid;
  int v = (i < n) ? cnt[i] : 0;
  int s = wave_incl_scan(v, lane);
  if (lane == 63) wsB[wid] = s;
  __syncthreads();
  int woff = 0;
  for (int w = 0; w < wid; w++) woff += wsB[w];
  int excl = base + woff + s - v;
  if (i < n) {
    ofs[i] = excl;
    inv[i] = 1.0f / (float)(v > 1 ? v : 1);
  }
}

// ---- reorder: bucket fill with NO atomics, 2 edges/thread ----
__global__ __launch_bounds__(256)
void reorder4_k(const int* __restrict__ e0, const int* __restrict__ e1,
                const int* __restrict__ e2, const int* __restrict__ e3,
                const int* __restrict__ ofs, const int* __restrict__ pos,
                int* __restrict__ bucket,
                int nE, int b0, int b1, int b2, int b3) {
  int y = blockIdx.y;
  const int* e = y == 0 ? e0 : y == 1 ? e1 : y == 2 ? e2 : e3;
  int base = y == 0 ? b0 : y == 1 ? b1 : y == 2 ? b2 : b3;
#pragma unroll
  for (int u = 0; u < 2; u++) {
    int i = blockIdx.x * 512 + u * 256 + threadIdx.x;
    if (i < nE) {
      int s = e[i];
      int d = e[nE + i];
      int p = pos[(size_t)y * nE + i];
      bucket[ofs[base + d] + p] = s;
    }
  }
}

// ---- one neighbor row (64B for this kh) accumulated into f32 partials ----
__device__ __forceinline__ void row_add(const ushort_t* rp, f32x2 a[4][4]) {
  uint4 v0 = *(const uint4*)(rp);
  uint4 v1 = *(const uint4*)(rp + 32);
  uint4 v2 = *(const uint4*)(rp + 64);
  uint4 v3 = *(const uint4*)(rp + 96);
  a[0][0] += (f32x2){bf_lo(v0.x), bf_hi(v0.x)};
  a[0][1] += (f32x2){bf_lo(v0.y), bf_hi(v0.y)};
  a[0][2] += (f32x2){bf_lo(v0.z), bf_hi(v0.z)};
  a[0][3] += (f32x2){bf_lo(v0.w), bf_hi(v0.w)};
  a[1][0] += (f32x2){bf_lo(v1.x), bf_hi(v1.x)};
  a[1][1] += (f32x2){bf_lo(v1.y), bf_hi(v1.y)};
  a[1][2] += (f32x2){bf_lo(v1.z), bf_hi(v1.z)};
  a[1][3] += (f32x2){bf_lo(v1.w), bf_hi(v1.w)};
  a[2][0] += (f32x2){bf_lo(v2.x), bf_hi(v2.x)};
  a[2][1] += (f32x2){bf_lo(v2.y), bf_hi(v2.y)};
  a[2][2] += (f32x2){bf_lo(v2.z), bf_hi(v2.z)};
  a[2][3] += (f32x2){bf_lo(v2.w), bf_hi(v2.w)};
  a[3][0] += (f32x2){bf_lo(v3.x), bf_hi(v3.x)};
  a[3][1] += (f32x2){bf_lo(v3.y), bf_hi(v3.y)};
  a[3][2] += (f32x2){bf_lo(v3.z), bf_hi(v3.z)};
  a[3][3] += (f32x2){bf_lo(v3.w), bf_hi(v3.w)};
}

// ---- in-register CSR gather -> MFMA A-fragments (R18-proven unroll-2) ----
__device__ __forceinline__ void gather_frags(const ushort_t* __restrict__ xsrc,
                                             const int* __restrict__ bucket,
                                             int beg, int c, float iv, int kh,
                                             uint4 out[4]) {
  f32x2 ac[4][4];
#pragma unroll
  for (int kk = 0; kk < 4; kk++)
#pragma unroll
    for (int p = 0; p < 4; p++) ac[kk][p] = (f32x2){0.f, 0.f};

  const ushort_t* base = xsrc + kh * 8;
  int j = 0;
  for (; j + 2 <= c; j += 2) {
    const ushort_t* r0 = base + (size_t)bucket[beg + j] * D128;
    const ushort_t* r1 = base + (size_t)bucket[beg + j + 1] * D128;
    uint4 v00 = *(const uint4*)(r0);
    uint4 v01 = *(const uint4*)(r0 + 32);
    uint4 v02 = *(const uint4*)(r0 + 64);
    uint4 v03 = *(const uint4*)(r0 + 96);
    uint4 v10 = *(const uint4*)(r1);
    uint4 v11 = *(const uint4*)(r1 + 32);
    uint4 v12 = *(const uint4*)(r1 + 64);
    uint4 v13 = *(const uint4*)(r1 + 96);
    {
      f32x2 t[4][4];
      (void)t;
    }
    // accumulate rows in sequential j order (bit-identical numerics)
    {
      // row 0
      ac[0][0] += (f32x2){bf_lo(v00.x), bf_hi(v00.x)};
      ac[0][1] += (f32x2){bf_lo(v00.y), bf_hi(v00.y)};
      ac[0][2] += (f32x2){bf_lo(v00.z), bf_hi(v00.z)};
      ac[0][3] += (f32x2){bf_lo(v00.w), bf_hi(v00.w)};
      ac[1][0] += (f32x2){bf_lo(v01.x), bf_hi(v01.x)};
      ac[1][1] += (f32x2){bf_lo(v01.y), bf_hi(v01.y)};
      ac[1][2] += (f32x2){bf_lo(v01.z), bf_hi(v01.z)};
      ac[1][3] += (f32x2){bf_lo(v01.w), bf_hi(v01.w)};
      ac[2][0] += (f32x2){bf_lo(v02.x), bf_hi(v02.x)};
      ac[2][1] += (f32x2){bf_lo(v02.y), bf_hi(v02.y)};
      ac[2][2] += (f32x2){bf_lo(v02.z), bf_hi(v02.z)};
      ac[2][3] += (f32x2){bf_lo(v02.w), bf_hi(v02.w)};
      ac[3][0] += (f32x2){bf_lo(v03.x), bf_hi(v03.x)};
      ac[3][1] += (f32x2){bf_lo(v03.y), bf_hi(v03.y)};
      ac[3][2] += (f32x2){bf_lo(v03.z), bf_hi(v03.z)};
      ac[3][3] += (f32x2){bf_lo(v03.w), bf_hi(v03.w)};
      // row 1
      ac[0][0] += (f32x2){bf_lo(v10.x), bf_hi(v10.x)};
      ac[0][1] += (f32x2){bf_lo(v10.y), bf_hi(v10.y)};
      ac[0][2] += (f32x2){bf_lo(v10.z), bf_hi(v10.z)};
      ac[0][3] += (f32x2){bf_lo(v10.w), bf_hi(v10.w)};
      ac[1][0] += (f32x2){bf_lo(v11.x), bf_hi(v11.x)};
      ac[1][1] += (f32x2){bf_lo(v11.y), bf_hi(v11.y)};
      ac[1][2] += (f32x2){bf_lo(v11.z), bf_hi(v11.z)};
      ac[1][3] += (f32x2){bf_lo(v11.w), bf_hi(v11.w)};
      ac[2][0] += (f32x2){bf_lo(v12.x), bf_hi(v12.x)};
      ac[2][1] += (f32x2){bf_lo(v12.y), bf_hi(v12.y)};
      ac[2][2] += (f32x2){bf_lo(v12.z), bf_hi(v12.z)};
      ac[2][3] += (f32x2){bf_lo(v12.w), bf_hi(v12.w)};
      ac[3][0] += (f32x2){bf_lo(v13.x), bf_hi(v13.x)};
      ac[3][1] += (f32x2){bf_lo(v13.y), bf_hi(v13.y)};
      ac[3][2] += (f32x2){bf_lo(v13.z), bf_hi(v13.z)};
      ac[3][3] += (f32x2){bf_lo(v13.w), bf_hi(v13.w)};
    }
  }
  if (j < c) {
    const ushort_t* r0 = base + (size_t)bucket[beg + j] * D128;
    row_add(r0, ac);
  }
#pragma unroll
  for (int kk = 0; kk < 4; kk++) {
    uint4 o;
    o.x = pack2(ac[kk][0][0] * iv, ac[kk][0][1] * iv);
    o.y = pack2(ac[kk][1][0] * iv, ac[kk][1][1] * iv);
    o.z = pack2(ac[kk][2][0] * iv, ac[kk][2][1] * iv);
    o.w = pack2(ac[kk][3][0] * iv, ac[kk][3][1] * iv);
    out[kk] = o;
  }
}

// ---- fused gather+SAGE, single edge type ----
struct SJob {
  const ushort_t* xs;   // gather source rows
  const int* ofs;
  const int* cnt;
  const float* inv;
  const ushort_t* xd;   // dense lin_r input
  const ushort_t* wl;
  const ushort_t* wr;
  const float* bias;
  ushort_t* out;
  int ntiles;
};

__device__ __forceinline__ void sage_single_fused(const SJob& J, char* smem,
                                                  const int* __restrict__ bucket) {
  const int tid = threadIdx.x;
  for (int c = tid; c < 4096; c += 1024) {
    int m = c >> 11, cc = c & 2047;
    int row = cc >> 4, slot = cc & 15;
    const ushort_t* W = m ? J.wr : J.wl;
    uint4 v = *((const uint4*)W + cc);
    *(uint4*)(smem + m * 32768 + row * 256 + ((slot ^ (row & 15)) << 4)) = v;
  }
  __syncthreads();

  int wid = tid >> 6, lane = tid & 63;
  int r = lane & 15, kh = lane >> 4;
  int tile = blockIdx.x * 16 + wid;
  if (tile >= J.ntiles) return;
  size_t n0 = (size_t)tile * 16;
  int node = (int)n0 + r;

  uint4 A4[4];
  gather_frags(J.xs, bucket, J.ofs[node], J.cnt[node], J.inv[node], kh, A4);

  const ushort_t* xp = J.xd + (n0 + r) * D128 + kh * 8;
  uint4 X4[4];
#pragma unroll
  for (int kk = 0; kk < 4; kk++) X4[kk] = *(const uint4*)(xp + kk * 32);

  f32x4 acc[8];
#pragma unroll
  for (int t = 0; t < 8; t++) acc[t] = (f32x4){0.f, 0.f, 0.f, 0.f};

#pragma unroll
  for (int kk = 0; kk < 4; kk++) {
    int so = (((kk << 2) + kh) ^ r) << 4;
    bf16x8 af = as_h(A4[kk]);
    bf16x8 xf = as_h(X4[kk]);
#pragma unroll
    for (int t = 0; t < 8; t++) {
      const char* p = smem + t * 4096 + r * 256 + so;
      bf16x8 bwl = *(const bf16x8*)(p);
      bf16x8 bwr = *(const bf16x8*)(p + 32768);
      acc[t] = __builtin_amdgcn_mfma_f32_16x16x32_bf16(af, bwl, acc[t], 0, 0, 0);
      acc[t] = __builtin_amdgcn_mfma_f32_16x16x32_bf16(xf, bwr, acc[t], 0, 0, 0);
    }
  }

  float s[4] = {0.f, 0.f, 0.f, 0.f};
#pragma unroll
  for (int t = 0; t < 8; t++) {
    float bv = J.bias[t * 16 + r];
#pragma unroll
    for (int q = 0; q < 4; q++) {
      float c = acc[t][q] + bv;
      acc[t][q] = c;
      s[q] += c * c;
    }
  }
#pragma unroll
  for (int off = 1; off < 16; off <<= 1) {
#pragma unroll
    for (int q = 0; q < 4; q++) s[q] += __shfl_xor(s[q], off);
  }
  float rn[4];
#pragma unroll
  for (int q = 0; q < 4; q++) rn[q] = 1.0f / fmaxf(sqrtf(s[q]), 1e-12f);

#pragma unroll
  for (int tp = 0; tp < 4; tp++) {
    int t0 = 2 * tp, t1 = 2 * tp + 1;
#pragma unroll
    for (int q = 0; q < 4; q++) {
      float a = fmaxf(acc[t0][q] * rn[q], 0.f);
      float b = fmaxf(acc[t1][q] * rn[q], 0.f);
      size_t nd = n0 + kh * 4 + q;
      store_pair_bf16(J.out + nd * D128, r, t0, t1, a, b);
    }
  }
}

// ---- fused gather+SAGE, dual edge type (app dst) ----
struct DJob {
  const ushort_t* xsA;
  const int* ofsA;
  const int* cntA;
  const float* invA;
  const ushort_t* xsB;
  const int* ofsB;
  const int* cntB;
  const float* invB;
  const ushort_t* xd;
  const ushort_t* wlA;
  const ushort_t* wrA;
  const ushort_t* wlB;
  const ushort_t* wrB;
  const float* biasA;
  const float* biasB;
  void* out;
  int ntiles;
};

template <int CLF>
__device__ __forceinline__ void sage_dual_fused(const DJob& J, char* smem,
                                                const int* __restrict__ bucket,
                                                const float* clfW, const float* clfb) {
  const int tid = threadIdx.x;
  for (int c = tid; c < 8192; c += 1024) {
    int m = c >> 11, cc = c & 2047;
    int row = cc >> 4, slot = cc & 15;
    const ushort_t* W = m == 0 ? J.wlA : m == 1 ? J.wrA : m == 2 ? J.wlB : J.wrB;
    uint4 v = *((const uint4*)W + cc);
    *(uint4*)(smem + m * 32768 + row * 256 + ((slot ^ (row & 15)) << 4)) = v;
  }
  __syncthreads();

  int wid = tid >> 6, lane = tid & 63;
  int r = lane & 15, kh = lane >> 4;
  int tile = blockIdx.x * 16 + wid;
  if (tile >= J.ntiles) return;
  size_t n0 = (size_t)tile * 16;
  int node = (int)n0 + r;

  uint4 A1[4], A3[4];
  gather_frags(J.xsA, bucket, J.ofsA[node], J.cntA[node], J.invA[node], kh, A1);
  gather_frags(J.xsB, bucket, J.ofsB[node], J.cntB[node], J.invB[node], kh, A3);

  const ushort_t* xp = J.xd + (n0 + r) * D128 + kh * 8;
  uint4 X4[4];
#pragma unroll
  for (int kk = 0; kk < 4; kk++) X4[kk] = *(const uint4*)(xp + kk * 32);

  f32x4 acc1[8], acc3[8];
#pragma unroll
  for (int t = 0; t < 8; t++) {
    acc1[t] = (f32x4){0.f, 0.f, 0.f, 0.f};
    acc3[t] = (f32x4){0.f, 0.f, 0.f, 0.f};
  }

#pragma unroll
  for (int kk = 0; kk < 4; kk++) {
    int so = (((kk << 2) + kh) ^ r) << 4;
    bf16x8 af1 = as_h(A1[kk]);
    bf16x8 af3 = as_h(A3[kk]);
    bf16x8 xf = as_h(X4[kk]);
#pragma unroll
    for (int t = 0; t < 8; t++) {
      const char* p = smem + t * 4096 + r * 256 + so;
      bf16x8 wla = *(const bf16x8*)(p);
      bf16x8 wra = *(const bf16x8*)(p + 32768);
      bf16x8 wlb = *(const bf16x8*)(p + 65536);
      bf16x8 wrb = *(const bf16x8*)(p + 98304);
      acc1[t] = __builtin_amdgcn_mfma_f32_16x16x32_bf16(af1, wla, acc1[t], 0, 0, 0);
      acc1[t] = __builtin_amdgcn_mfma_f32_16x16x32_bf16(xf, wra, acc1[t], 0, 0, 0);
      acc3[t] = __builtin_amdgcn_mfma_f32_16x16x32_bf16(af3, wlb, acc3[t], 0, 0, 0);
      acc3[t] = __builtin_amdgcn_mfma_f32_16x16x32_bf16(xf, wrb, acc3[t], 0, 0, 0);
    }
  }

  float s1[4] = {0.f, 0.f, 0.f, 0.f}, s3[4] = {0.f, 0.f, 0.f, 0.f};
#pragma unroll
  for (int t = 0; t < 8; t++) {
    float bvA = J.biasA[t * 16 + r];
    float bvB = J.biasB[t * 16 + r];
#pragma unroll
    for (int q = 0; q < 4; q++) {
      float c1 = acc1[t][q] + bvA;
      acc1[t][q] = c1; s1[q] += c1 * c1;
      float c3 = acc3[t][q] + bvB;
      acc3[t][q] = c3; s3[q] += c3 * c3;
    }
  }
#pragma unroll
  for (int off = 1; off < 16; off <<= 1) {
#pragma unroll
    for (int q = 0; q < 4; q++) {
      s1[q] += __shfl_xor(s1[q], off);
      s3[q] += __shfl_xor(s3[q], off);
    }
  }
  float rn1[4], rn3[4];
#pragma unroll
  for (int q = 0; q < 4; q++) {
    rn1[q] = 1.0f / fmaxf(sqrtf(s1[q]), 1e-12f);
    rn3[q] = 1.0f / fmaxf(sqrtf(s3[q]), 1e-12f);
  }

  if (CLF) {
    float w0[8], w1[8];
#pragma unroll
    for (int t = 0; t < 8; t++) {
      w0[t] = clfW[t * 16 + r];
      w1[t] = clfW[D128 + t * 16 + r];
    }
    float p0[4] = {0.f, 0.f, 0.f, 0.f}, p1[4] = {0.f, 0.f, 0.f, 0.f};
#pragma unroll
    for (int t = 0; t < 8; t++) {
#pragma unroll
      for (int q = 0; q < 4; q++) {
        float val = acc1[t][q] * rn1[q] + acc3[t][q] * rn3[q];
        p0[q] += val * w0[t];
        p1[q] += val * w1[t];
      }
    }
#pragma unroll
    for (int off = 1; off < 16; off <<= 1) {
#pragma unroll
      for (int q = 0; q < 4; q++) {
        p0[q] += __shfl_xor(p0[q], off);
        p1[q] += __shfl_xor(p1[q], off);
      }
    }
    if (r == 0) {
      float cb0 = clfb[0], cb1 = clfb[1];
#pragma unroll
      for (int q = 0; q < 4; q++) {
        size_t nd = n0 + kh * 4 + q;
        float2 o; o.x = p0[q] + cb0; o.y = p1[q] + cb1;
        *(float2*)((float*)J.out + nd * 2) = o;
      }
    }
  } else {
#pragma unroll
    for (int tp = 0; tp < 4; tp++) {
      int t0 = 2 * tp, t1 = 2 * tp + 1;
#pragma unroll
      for (int q = 0; q < 4; q++) {
        float a = fmaxf(acc1[t0][q] * rn1[q] + acc3[t0][q] * rn3[q], 0.f);
        float b = fmaxf(acc1[t1][q] * rn1[q] + acc3[t1][q] * rn3[q], 0.f);
        size_t nd = n0 + kh * 4 + q;
        store_pair_bf16((ushort_t*)J.out + nd * D128, r, t0, t1, a, b);
      }
    }
  }
}

// ---- L1: y=0 dual app (h1a), y=1 mer single, y=2 dev single ----
__global__ __launch_bounds__(1024)
void sageL1_k(DJob DJ, SJob S1, SJob S2, const int* __restrict__ bucket) {
  extern __shared__ char smem[];
  int y = blockIdx.y;
  if (y == 0) {
    sage_dual_fused<0>(DJ, smem, bucket, nullptr, nullptr);
  } else {
    const SJob& J = (y == 1) ? S1 : S2;
    if (blockIdx.x * 16 >= J.ntiles) return;
    sage_single_fused(J, smem, bucket);
  }
}

// ---- L2: dual + classifier ----
__global__ __launch_bounds__(1024)
void sageL2_k(DJob DJ, const int* __restrict__ bucket,
              const float* __restrict__ clfW, const float* __restrict__ clfb) {
  extern __shared__ char smem[];
  sage_dual_fused<1>(DJ, smem, bucket, clfW, clfb);
}

extern "C" void kernel_launch(void* const* d_in, const int* in_sizes, int n_in,
                              void* d_out, int out_size, void* d_ws, size_t ws_size,
                              hipStream_t stream) {
  const float* emb_app = (const float*)d_in[0];
  const float* emb_mer = (const float*)d_in[1];
  const float* emb_dev = (const float*)d_in[2];
  const float* c1Wl = (const float*)d_in[3];
  const float* c1bl = (const float*)d_in[4];
  const float* c1Wr = (const float*)d_in[5];
  const float* c2Wl = (const float*)d_in[6];
  const float* c2bl = (const float*)d_in[7];
  const float* c2Wr = (const float*)d_in[8];
  const float* clfW = (const float*)d_in[9];
  const float* clfb = (const float*)d_in[10];
  const int* e0 = (const int*)d_in[11];
  const int* e1 = (const int*)d_in[12];
  const int* e2 = (const int*)d_in[13];
  const int* e3 = (const int*)d_in[14];

  const int NA = in_sizes[0] / D128;
  const int NM = in_sizes[1] / D128;
  const int ND = in_sizes[2] / D128;
  const int E = in_sizes[11] / 2;
  float* out = (float*)d_out;

  char* wsb = (char*)d_ws;
  size_t off = 0;
  auto alloc = [&](size_t bytes) -> char* {
    char* p = wsb + off;
    off += (bytes + 511) & ~(size_t)511;
    return p;
  };
  ushort_t* wl1 = (ushort_t*)alloc((size_t)4 * 16384 * 2);
  ushort_t* wr1 = (ushort_t*)alloc((size_t)4 * 16384 * 2);
  ushort_t* wl2 = (ushort_t*)alloc((size_t)4 * 16384 * 2);
  ushort_t* wr2 = (ushort_t*)alloc((size_t)4 * 16384 * 2);

  // embeddings bf16 (live through layer 1)
  size_t embBytes = ((size_t)NM + ND + NA) * D128 * 2;
  char* big = alloc(embBytes);
  ushort_t* emer = (ushort_t*)big;
  ushort_t* edev = emer + (size_t)NM * D128;
  ushort_t* eapp = edev + (size_t)ND * D128;

  ushort_t* h1m = (ushort_t*)alloc((size_t)NM * D128 * 2);
  ushort_t* h1d = (ushort_t*)alloc((size_t)ND * D128 * 2);
  ushort_t* h1a = (ushort_t*)alloc((size_t)NA * D128 * 2);
  int ncnt = NM + NA + ND + NA;
  int nb = (ncnt + 255) / 256;
  int* cnt = (int*)alloc((size_t)ncnt * 4);
  float* inv = (float*)alloc((size_t)ncnt * 4);
  int* ofs = (int*)alloc((size_t)ncnt * 4);
  int* bsum = (int*)alloc((size_t)nb * 4);
  int* pos = (int*)alloc((size_t)4 * E * 4);
  int* bucket = (int*)alloc((size_t)4 * E * 4);
  (void)ws_size;  // ~205 MB

  int b0 = 0, b1 = NM, b2 = NM + NA, b3 = NM + NA + ND;

  const int SMEM2 = 131072;
  hipFuncSetAttribute((const void*)sageL1_k,
                      hipFuncAttributeMaxDynamicSharedMemorySize, SMEM2);
  hipFuncSetAttribute((const void*)sageL2_k,
                      hipFuncAttributeMaxDynamicSharedMemorySize, SMEM2);

  // ---- weights cvt + interleaved {embedding cvt ∥ poscount} ----
  dim3 wg(64, 4);
  cvtW_k<<<wg, 256, 0, stream>>>(c1Wl, c1Wr, c2Wl, c2Wr, wl1, wr1, wl2, wr2);
  hipMemsetAsync(cnt, 0, (size_t)ncnt * 4, stream);
  int na4 = NA * 32, nm4 = NM * 32, nd4 = ND * 32;
  int nbC = (na4 + nm4 + nd4 + 255) / 256;
  int nbE4 = (E + 1023) / 1024;
  int nbA = 4 * nbE4;
  pre2_k<<<nbC + nbA, 256, 0, stream>>>(
      emb_app, emb_mer, emb_dev, eapp, emer, edev, na4, nm4, nd4, nbC,
      e0 + E, e1 + E, e2 + E, e3 + E, cnt, pos, E, nbE4, nbA, b0, b1, b2, b3);
  scan1_k<<<nb, 256, 0, stream>>>(cnt, bsum, ncnt);
  scan2_k<<<nb, 256, 0, stream>>>(cnt, bsum, ofs, inv, ncnt);
  dim3 eg((E + 511) / 512, 4);
  reorder4_k<<<eg, 256, 0, stream>>>(e0, e1, e2, e3, ofs, pos, bucket,
                                     E, b0, b1, b2, b3);

  auto g16 = [](int nt) { return (nt + 15) / 16; };
  int tA = NA / 16, tM = NM / 16, tD = ND / 16;

  // ---- layer 1: all 4 gathers fused into the 3 sage jobs, one launch ----
  {
    DJob DJ;
    DJ.xsA = emer; DJ.ofsA = ofs + b1; DJ.cntA = cnt + b1; DJ.invA = inv + b1;
    DJ.xsB = edev; DJ.ofsB = ofs + b3; DJ.cntB = cnt + b3; DJ.invB = inv + b3;
    DJ.xd = eapp;
    DJ.wlA = wl1 + 1 * 16384; DJ.wrA = wr1 + 1 * 16384;
    DJ.wlB = wl1 + 3 * 16384; DJ.wrB = wr1 + 3 * 16384;
    DJ.biasA = c1bl + 1 * D128; DJ.biasB = c1bl + 3 * D128;
    DJ.out = h1a; DJ.ntiles = tA;
    SJob S1;
    S1.xs = eapp; S1.ofs = ofs + b0; S1.cnt = cnt + b0; S1.inv = inv + b0;
    S1.xd = emer; S1.wl = wl1 + 0 * 16384; S1.wr = wr1 + 0 * 16384;
    S1.bias = c1bl + 0 * D128; S1.out = h1m; S1.ntiles = tM;
    SJob S2;
    S2.xs = eapp; S2.ofs = ofs + b2; S2.cnt = cnt + b2; S2.inv = inv + b2;
    S2.xd = edev; S2.wl = wl1 + 2 * 16384; S2.wr = wr1 + 2 * 16384;
    S2.bias = c1bl + 2 * D128; S2.out = h1d; S2.ntiles = tD;
    dim3 sg(g16(tA), 3);
    sageL1_k<<<sg, 1024, SMEM2, stream>>>(DJ, S1, S2, bucket);
  }

  // ---- layer 2: fused gathers (h1m/h1d post-relu) + dual + classifier ----
  {
    DJob DJ;
    DJ.xsA = h1m; DJ.ofsA = ofs + b1; DJ.cntA = cnt + b1; DJ.invA = inv + b1;
    DJ.xsB = h1d; DJ.ofsB = ofs + b3; DJ.cntB = cnt + b3; DJ.invB = inv + b3;
    DJ.xd = h1a;
    DJ.wlA = wl2 + 1 * 16384; DJ.wrA = wr2 + 1 * 16384;
    DJ.wlB = wl2 + 3 * 16384; DJ.wrB = wr2 + 3 * 16384;
    DJ.biasA = c2bl + 1 * D128; DJ.biasB = c2bl + 3 * D128;
    DJ.out = out; DJ.ntiles = tA;
    sageL2_k<<<g16(tA), 1024, SMEM2, stream>>>(DJ, bucket, clfW, clfb);
  }
}